// Round 13
// baseline (137.853 us; speedup 1.0000x reference)
//
#include <hip/hip_runtime.h>
#include <hip/hip_bf16.h>

// Problem constants
#define HID 512
#define SEQ 2048
#define NG 32            // (B*NUM_HEADS) after the faithful-to-source flat reshape
#define HD 64
#define MROWS 8192       // B*SEQ
#define LDP 72           // padded LDS row stride (elems) = 144B
// 1/sqrt(512) * log2(e): folded into Q so softmax is exp2(s)
#define QSC 0.0637587178f

typedef __bf16 bf16x8 __attribute__((ext_vector_type(8)));
typedef float f32x4 __attribute__((ext_vector_type(4)));

#define MFMA(a, b, c) __builtin_amdgcn_mfma_f32_16x16x32_bf16((a), (b), (c), 0, 0, 0)

// ---------------------------------------------------------------------------
// prep: f32 -> bf16 vectorized converts
// ---------------------------------------------------------------------------
__global__ __launch_bounds__(256) void conv_x(const float* __restrict__ src,
                                              __hip_bfloat16* __restrict__ dst, int n4) {
    int stride = gridDim.x * 256;
    for (int i = blockIdx.x * 256 + threadIdx.x; i < n4; i += stride) {
        float4 v = *(const float4*)(src + (size_t)i * 4);
        union { __hip_bfloat16 h[4]; uint2 u; } p;
        p.h[0] = __float2bfloat16(v.x); p.h[1] = __float2bfloat16(v.y);
        p.h[2] = __float2bfloat16(v.z); p.h[3] = __float2bfloat16(v.w);
        *(uint2*)(dst + (size_t)i * 4) = p.u;
    }
}

__global__ __launch_bounds__(256) void conv_w(const float* __restrict__ a,
                                              const float* __restrict__ b,
                                              const float* __restrict__ c,
                                              const float* __restrict__ d,
                                              __hip_bfloat16* __restrict__ out) {
    int which = blockIdx.y;
    const float* s = which == 0 ? a : (which == 1 ? b : (which == 2 ? c : d));
    __hip_bfloat16* o = out + (size_t)which * (HID * HID);
    int i = blockIdx.x * 256 + threadIdx.x;   // 65536 float4 per W
    float4 v = *(const float4*)(s + (size_t)i * 4);
    union { __hip_bfloat16 h[4]; uint2 u; } p;
    p.h[0] = __float2bfloat16(v.x); p.h[1] = __float2bfloat16(v.y);
    p.h[2] = __float2bfloat16(v.z); p.h[3] = __float2bfloat16(v.w);
    *(uint2*)(o + (size_t)i * 4) = p.u;
}

// ---------------------------------------------------------------------------
// Fused QKV GEMM with T14 register prefetch across the stage barrier.
// q pre-scaled by QSC; v written transposed per head: vT[g][d][i].
// ---------------------------------------------------------------------------
__global__ __launch_bounds__(256) void gemm_qkv_fused(
        const __hip_bfloat16* __restrict__ Xb,
        const __hip_bfloat16* __restrict__ Wqb, const __hip_bfloat16* __restrict__ Wkb,
        const __hip_bfloat16* __restrict__ Wvb,
        const float* __restrict__ bq, const float* __restrict__ bk, const float* __restrict__ bv,
        __hip_bfloat16* __restrict__ qout, __hip_bfloat16* __restrict__ kout,
        __hip_bfloat16* __restrict__ vT) {
    __shared__ __hip_bfloat16 Xs[64][LDP];
    __shared__ __hip_bfloat16 Wqs[64][LDP];
    __shared__ __hip_bfloat16 Wks[64][LDP];
    __shared__ __hip_bfloat16 Wvs[64][LDP];
    const int tid = threadIdx.x;
    const int w = tid >> 6, l = tid & 63;
    const int row0 = blockIdx.x * 64, col0 = blockIdx.y * 64;

    const int r0 = tid >> 3, r1 = (tid + 256) >> 3;
    const int cc0 = (tid & 7) * 8;
    uint4 px0, px1, pq0, pq1, pk0, pk1, pv0, pv1;
    {
        px0 = *(const uint4*)(Xb  + (size_t)(row0 + r0) * HID + cc0);
        px1 = *(const uint4*)(Xb  + (size_t)(row0 + r1) * HID + cc0);
        pq0 = *(const uint4*)(Wqb + (size_t)(col0 + r0) * HID + cc0);
        pq1 = *(const uint4*)(Wqb + (size_t)(col0 + r1) * HID + cc0);
        pk0 = *(const uint4*)(Wkb + (size_t)(col0 + r0) * HID + cc0);
        pk1 = *(const uint4*)(Wkb + (size_t)(col0 + r1) * HID + cc0);
        pv0 = *(const uint4*)(Wvb + (size_t)(col0 + r0) * HID + cc0);
        pv1 = *(const uint4*)(Wvb + (size_t)(col0 + r1) * HID + cc0);
    }

    f32x4 aq[4] = {}, ak[4] = {}, av[4] = {};
    for (int kt = 0; kt < 8; ++kt) {
        __syncthreads();
        *(uint4*)&Xs[r0][cc0]  = px0;  *(uint4*)&Xs[r1][cc0]  = px1;
        *(uint4*)&Wqs[r0][cc0] = pq0;  *(uint4*)&Wqs[r1][cc0] = pq1;
        *(uint4*)&Wks[r0][cc0] = pk0;  *(uint4*)&Wks[r1][cc0] = pk1;
        *(uint4*)&Wvs[r0][cc0] = pv0;  *(uint4*)&Wvs[r1][cc0] = pv1;
        __syncthreads();
        if (kt < 7) {
            size_t go = (size_t)(kt + 1) * 64 + cc0;
            px0 = *(const uint4*)(Xb  + (size_t)(row0 + r0) * HID + go);
            px1 = *(const uint4*)(Xb  + (size_t)(row0 + r1) * HID + go);
            pq0 = *(const uint4*)(Wqb + (size_t)(col0 + r0) * HID + go);
            pq1 = *(const uint4*)(Wqb + (size_t)(col0 + r1) * HID + go);
            pk0 = *(const uint4*)(Wkb + (size_t)(col0 + r0) * HID + go);
            pk1 = *(const uint4*)(Wkb + (size_t)(col0 + r1) * HID + go);
            pv0 = *(const uint4*)(Wvb + (size_t)(col0 + r0) * HID + go);
            pv1 = *(const uint4*)(Wvb + (size_t)(col0 + r1) * HID + go);
        }
        for (int dk = 0; dk < 2; ++dk) {
            bf16x8 a = *(const bf16x8*)&Xs[w * 16 + (l & 15)][dk * 32 + 8 * (l >> 4)];
            for (int nt = 0; nt < 4; ++nt) {
                int rr = nt * 16 + (l & 15), cc = dk * 32 + 8 * (l >> 4);
                aq[nt] = MFMA(a, *(const bf16x8*)&Wqs[rr][cc], aq[nt]);
                ak[nt] = MFMA(a, *(const bf16x8*)&Wks[rr][cc], ak[nt]);
                av[nt] = MFMA(a, *(const bf16x8*)&Wvs[rr][cc], av[nt]);
            }
        }
    }
    // epilogue
    const int g = row0 >> 8;
    const int rbase = (row0 & 255) + w * 16 + 4 * (l >> 4);
    for (int nt = 0; nt < 4; ++nt) {
        int n = col0 + nt * 16 + (l & 15);
        float bqv = bq[n], bkv = bk[n], bvv = bv[n];
        int d = n & 63;   // col0 is a multiple of 64
        for (int jj = 0; jj < 4; ++jj) {
            int r = row0 + w * 16 + 4 * (l >> 4) + jj;
            qout[(size_t)r * HID + n] = __float2bfloat16((aq[nt][jj] + bqv) * QSC);
            kout[(size_t)r * HID + n] = __float2bfloat16(ak[nt][jj] + bkv);
            vT[(size_t)g * (HD * SEQ) + (size_t)d * SEQ + (rbase + jj) * 8 + blockIdx.y] =
                __float2bfloat16(av[nt][jj] + bvv);
        }
    }
}

// ---------------------------------------------------------------------------
// GEMM: out_f32[M x 512] = X_bf16 @ Wo_bf16^T + bo, with T14 reg prefetch.
// ---------------------------------------------------------------------------
__global__ __launch_bounds__(256) void gemm_out(const __hip_bfloat16* __restrict__ X,
                                                const __hip_bfloat16* __restrict__ W,
                                                const float* __restrict__ bias,
                                                float* __restrict__ out) {
    __shared__ __hip_bfloat16 Xs[64][LDP];
    __shared__ __hip_bfloat16 Ws[64][LDP];
    const int tid = threadIdx.x;
    const int w = tid >> 6, l = tid & 63;
    const int row0 = blockIdx.x * 64, col0 = blockIdx.y * 64;

    const int r0 = tid >> 3, r1 = (tid + 256) >> 3;
    const int cc0 = (tid & 7) * 8;
    uint4 px0 = *(const uint4*)(X + (size_t)(row0 + r0) * HID + cc0);
    uint4 px1 = *(const uint4*)(X + (size_t)(row0 + r1) * HID + cc0);
    uint4 pw0 = *(const uint4*)(W + (size_t)(col0 + r0) * HID + cc0);
    uint4 pw1 = *(const uint4*)(W + (size_t)(col0 + r1) * HID + cc0);

    f32x4 acc[4] = {};
    for (int kt = 0; kt < 8; ++kt) {
        __syncthreads();
        *(uint4*)&Xs[r0][cc0] = px0;  *(uint4*)&Xs[r1][cc0] = px1;
        *(uint4*)&Ws[r0][cc0] = pw0;  *(uint4*)&Ws[r1][cc0] = pw1;
        __syncthreads();
        if (kt < 7) {
            size_t go = (size_t)(kt + 1) * 64 + cc0;
            px0 = *(const uint4*)(X + (size_t)(row0 + r0) * HID + go);
            px1 = *(const uint4*)(X + (size_t)(row0 + r1) * HID + go);
            pw0 = *(const uint4*)(W + (size_t)(col0 + r0) * HID + go);
            pw1 = *(const uint4*)(W + (size_t)(col0 + r1) * HID + go);
        }
        for (int dk = 0; dk < 2; ++dk) {
            bf16x8 a = *(const bf16x8*)&Xs[w * 16 + (l & 15)][dk * 32 + 8 * (l >> 4)];
            for (int nt = 0; nt < 4; ++nt) {
                bf16x8 b = *(const bf16x8*)&Ws[nt * 16 + (l & 15)][dk * 32 + 8 * (l >> 4)];
                acc[nt] = MFMA(a, b, acc[nt]);
            }
        }
    }
    for (int nt = 0; nt < 4; ++nt) {
        int n = col0 + nt * 16 + (l & 15);
        float bv = bias[n];
        for (int jj = 0; jj < 4; ++jj) {
            int r = row0 + w * 16 + 4 * (l >> 4) + jj;
            out[(size_t)r * HID + n] = acc[nt][jj] + bv;
        }
    }
}

// ---------------------------------------------------------------------------
// Attention, split-K (flash-decoding): grid = 32 heads x 16 q-tiles x 2 key
// halves = 1024 blocks (4/CU, vs 512 = 2/CU before: occupancy was the round-12
// limiter at 17.9%). Each block runs 16 k-tiles of the swapped-QK^T in-register
// pipeline (round-12-verified) and writes UNNORMALIZED partials:
//   pO[ks][g][d][i] (bf16)  and  lp[ks][g][i] (f32).
// attn_reduce then combines (O0+O1)/(l0+l1). bf16 partial error ~0.2% rel of
// O ~ l*avg divides out to ~2e-5 absolute: negligible vs threshold.
// ---------------------------------------------------------------------------
__global__ __launch_bounds__(256) void attn(const __hip_bfloat16* __restrict__ qg,
                                            const __hip_bfloat16* __restrict__ kg,
                                            const __hip_bfloat16* __restrict__ vT,
                                            const int* __restrict__ mask,
                                            __hip_bfloat16* __restrict__ pO0,
                                            __hip_bfloat16* __restrict__ pO1,
                                            float* __restrict__ lp) {
    __shared__ __hip_bfloat16 Ks[2][64][LDP];
    __shared__ __hip_bfloat16 VTs[2][64][LDP];
    __shared__ float sb[2][64];

    const int tid = threadIdx.x;
    const int w = tid >> 6, l = tid & 63;
    const int h = l >> 4, q = l & 15;
    // XCD-chunked swizzle: 1024 blocks % 8 == 0 -> bijective
    const int bid = (blockIdx.x & 7) * 128 + (blockIdx.x >> 3);
    const int g = bid >> 5, qt = (bid >> 1) & 15, ks = bid & 1;
    const size_t hb = (size_t)g * (SEQ * HD);
    const int tb = ks * 16;                 // first k-tile of this half

    // Q fragments in registers (one-time global read, L2-resident)
    bf16x8 qf[2][2];
    for (int m = 0; m < 2; ++m)
        for (int dk = 0; dk < 2; ++dk)
            qf[m][dk] = *(const bf16x8*)(qg + hb +
                (size_t)(qt * 128 + w * 32 + m * 16 + q) * HD + dk * 32 + 8 * h);

    const int r0 = tid >> 3, r1 = (tid + 256) >> 3;
    const int cc0 = (tid & 7) * 8;
    // permuted V dest base: keys cc0..cc0+3 -> cA..cA+3, cc0+4..+7 -> cA+8..+11
    const int ntc = cc0 >> 4;
    const int cA = (ntc & 1) * 32 + ((cc0 >> 2) & 3) * 8 + (ntc >> 1) * 4;

    const __bf16 kOne = (__bf16)1.0f;
    const bf16x8 ones = {kOne, kOne, kOne, kOne, kOne, kOne, kOne, kOne};

    f32x4 acc[2][4] = {};
    f32x4 lsum[2] = {};

    // ---- prologue: tile tb into buf 0; tile tb+1 into regs ----
    uint4 kp0 = *(const uint4*)(kg + hb + (size_t)(tb * 64 + r0) * HD + cc0);
    uint4 kp1 = *(const uint4*)(kg + hb + (size_t)(tb * 64 + r1) * HD + cc0);
    uint4 vp0 = *(const uint4*)(vT + hb + (size_t)r0 * SEQ + tb * 64 + cc0);
    uint4 vp1 = *(const uint4*)(vT + hb + (size_t)r1 * SEQ + tb * 64 + cc0);
    int mpre = (tid < 64) ? mask[tb * 64 + tid] : 0;

    *(uint4*)&Ks[0][r0][cc0] = kp0;
    *(uint4*)&Ks[0][r1][cc0] = kp1;
    *(uint2*)&VTs[0][r0][cA]     = make_uint2(vp0.x, vp0.y);
    *(uint2*)&VTs[0][r0][cA + 8] = make_uint2(vp0.z, vp0.w);
    *(uint2*)&VTs[0][r1][cA]     = make_uint2(vp1.x, vp1.y);
    *(uint2*)&VTs[0][r1][cA + 8] = make_uint2(vp1.z, vp1.w);
    if (tid < 64) sb[0][tid] = mpre ? 0.f : -1e38f;

    kp0 = *(const uint4*)(kg + hb + (size_t)((tb + 1) * 64 + r0) * HD + cc0);
    kp1 = *(const uint4*)(kg + hb + (size_t)((tb + 1) * 64 + r1) * HD + cc0);
    vp0 = *(const uint4*)(vT + hb + (size_t)r0 * SEQ + (tb + 1) * 64 + cc0);
    vp1 = *(const uint4*)(vT + hb + (size_t)r1 * SEQ + (tb + 1) * 64 + cc0);
    if (tid < 64) mpre = mask[(tb + 1) * 64 + tid];
    __syncthreads();

    for (int kt = 0; kt < 16; ++kt) {
        const int cur = kt & 1;
        if (kt < 15) {
            *(uint4*)&Ks[cur ^ 1][r0][cc0] = kp0;
            *(uint4*)&Ks[cur ^ 1][r1][cc0] = kp1;
            *(uint2*)&VTs[cur ^ 1][r0][cA]     = make_uint2(vp0.x, vp0.y);
            *(uint2*)&VTs[cur ^ 1][r0][cA + 8] = make_uint2(vp0.z, vp0.w);
            *(uint2*)&VTs[cur ^ 1][r1][cA]     = make_uint2(vp1.x, vp1.y);
            *(uint2*)&VTs[cur ^ 1][r1][cA + 8] = make_uint2(vp1.z, vp1.w);
            if (tid < 64) sb[cur ^ 1][tid] = mpre ? 0.f : -1e38f;
        }
        if (kt < 14) {
            const int tt = tb + kt + 2;
            const size_t ko = hb + (size_t)tt * 64 * HD;
            kp0 = *(const uint4*)(kg + ko + (size_t)r0 * HD + cc0);
            kp1 = *(const uint4*)(kg + ko + (size_t)r1 * HD + cc0);
            vp0 = *(const uint4*)(vT + hb + (size_t)r0 * SEQ + tt * 64 + cc0);
            vp1 = *(const uint4*)(vT + hb + (size_t)r1 * SEQ + tt * 64 + cc0);
            if (tid < 64) mpre = mask[tt * 64 + tid];
        }

        // S^T = K Q^T, accumulator init = per-key mask bias (vector read)
        f32x4 sacc[2][4];
        for (int nt = 0; nt < 4; ++nt) {
            f32x4 binit = *(const f32x4*)&sb[cur][nt * 16 + 4 * h];
            sacc[0][nt] = binit;
            sacc[1][nt] = binit;
        }
        for (int dk = 0; dk < 2; ++dk) {
            for (int nt = 0; nt < 4; ++nt) {
                bf16x8 kf = *(const bf16x8*)&Ks[cur][nt * 16 + q][dk * 32 + 8 * h];
                sacc[0][nt] = MFMA(kf, qf[0][dk], sacc[0][nt]);
                sacc[1][nt] = MFMA(kf, qf[1][dk], sacc[1][nt]);
            }
        }
        // p = exp2(s^T) packed straight into PV A-fragments (in registers)
        union pk_t { bf16x8 v; __hip_bfloat16 hh[8]; } pa[2][2];
        for (int m = 0; m < 2; ++m)
            for (int kk = 0; kk < 2; ++kk)
                for (int j = 0; j < 4; ++j) {
                    pa[m][kk].hh[j]     = __float2bfloat16(exp2f(sacc[m][kk][j]));
                    pa[m][kk].hh[j + 4] = __float2bfloat16(exp2f(sacc[m][kk + 2][j]));
                }
        // acc += P @ V ; lsum += P @ ones  (V columns permuted to match)
        for (int kk = 0; kk < 2; ++kk) {
            lsum[0] = MFMA(pa[0][kk].v, ones, lsum[0]);
            lsum[1] = MFMA(pa[1][kk].v, ones, lsum[1]);
            for (int dt = 0; dt < 4; ++dt) {
                bf16x8 bv = *(const bf16x8*)&VTs[cur][dt * 16 + q][kk * 32 + 8 * h];
                acc[0][dt] = MFMA(pa[0][kk].v, bv, acc[0][dt]);
                acc[1][dt] = MFMA(pa[1][kk].v, bv, acc[1][dt]);
            }
        }
        __syncthreads();   // writes to buf[cur^1] done; reads of buf[cur] done
    }

    // write unnormalized partials. Every lane with the same (h) holds the
    // same lsum (all-ones B makes all columns equal); only q==0 lanes write.
    __hip_bfloat16* pO = ks ? pO1 : pO0;
    float* lph = lp + (size_t)ks * (NG * SEQ) + (size_t)g * SEQ;
    for (int m = 0; m < 2; ++m) {
        const int ibase = qt * 128 + w * 32 + m * 16 + 4 * h;
        if (q == 0)
            *(float4*)(lph + ibase) = float4{lsum[m][0], lsum[m][1], lsum[m][2], lsum[m][3]};
        for (int dt = 0; dt < 4; ++dt) {
            int d = dt * 16 + q;
            union { __hip_bfloat16 hh[4]; uint2 u; } o;
            for (int jj = 0; jj < 4; ++jj)
                o.hh[jj] = __float2bfloat16(acc[m][dt][jj]);
            *(uint2*)(pO + (size_t)g * (HD * SEQ) + (size_t)d * SEQ + ibase) = o.u;
        }
    }
}

// ---------------------------------------------------------------------------
// Combine split-K partials: wvt = (O0 + O1) / (l0 + l1). 4M outputs, 8/thread.
// ---------------------------------------------------------------------------
__global__ __launch_bounds__(256) void attn_reduce(
        const __hip_bfloat16* __restrict__ pO0, const __hip_bfloat16* __restrict__ pO1,
        const float* __restrict__ lp, __hip_bfloat16* __restrict__ wvt) {
    const size_t f = ((size_t)blockIdx.x * 256 + threadIdx.x) * 8;
    const int i = (int)(f & (SEQ - 1));       // within-head query index (8-aligned)
    const int g = (int)(f >> 17);             // head = f / (64*2048)
    const float* l0 = lp + (size_t)g * SEQ + i;
    const float* l1 = lp + (size_t)(NG * SEQ) + (size_t)g * SEQ + i;
    float4 a0 = *(const float4*)l0, a1 = *(const float4*)(l0 + 4);
    float4 b0 = *(const float4*)l1, b1 = *(const float4*)(l1 + 4);
    float linv[8] = {1.f / (a0.x + b0.x), 1.f / (a0.y + b0.y),
                     1.f / (a0.z + b0.z), 1.f / (a0.w + b0.w),
                     1.f / (a1.x + b1.x), 1.f / (a1.y + b1.y),
                     1.f / (a1.z + b1.z), 1.f / (a1.w + b1.w)};
    union u8_t { uint4 u; __hip_bfloat16 h[8]; } o0, o1, r;
    o0.u = *(const uint4*)(pO0 + f);
    o1.u = *(const uint4*)(pO1 + f);
    for (int j = 0; j < 8; ++j)
        r.h[j] = __float2bfloat16(
            (__bfloat162float(o0.h[j]) + __bfloat162float(o1.h[j])) * linv[j]);
    *(uint4*)(wvt + f) = r.u;
}

// ---------------------------------------------------------------------------
// ws layout (26.5 MB peak): Xb [0,8MB) -> pO0 during attn; W bf16 [8,10MB);
// qb [10,18MB); kb [18,26MB) -> wvt after attn; lp [26,26.5MB).
// d_out: vT [0,8MB), pO1 [8,16MB) — both dead before gemm_out overwrites.
// ---------------------------------------------------------------------------
extern "C" void kernel_launch(void* const* d_in, const int* in_sizes, int n_in,
                              void* d_out, int out_size, void* d_ws, size_t ws_size,
                              hipStream_t stream) {
    const float* lstm = (const float*)d_in[0];
    const int* mask = (const int*)d_in[1];
    const float* Wq = (const float*)d_in[2]; const float* bq = (const float*)d_in[3];
    const float* Wk = (const float*)d_in[4]; const float* bk = (const float*)d_in[5];
    const float* Wv = (const float*)d_in[6]; const float* bv = (const float*)d_in[7];
    const float* Wo = (const float*)d_in[8]; const float* bo = (const float*)d_in[9];
    float* out = (float*)d_out;

    const size_t NX = (size_t)MROWS * HID;    // 4M elems
    const size_t NW = (size_t)HID * HID;      // 256K elems
    __hip_bfloat16* Xb  = (__hip_bfloat16*)d_ws;            // 4M elems (8MB)
    __hip_bfloat16* Wqb = Xb + NX;                          // 256K
    __hip_bfloat16* Wkb = Wqb + NW;
    __hip_bfloat16* Wvb = Wkb + NW;
    __hip_bfloat16* Wob = Wvb + NW;
    __hip_bfloat16* qb  = Wob + NW;                         // 4M
    __hip_bfloat16* kb  = qb + NX;                          // 4M
    float*          lpp = (float*)(kb + NX);                // 2*64K f32 (512KB)
    __hip_bfloat16* vT  = (__hip_bfloat16*)d_out;           // scratch d_out[0,8MB)
    __hip_bfloat16* pO0 = Xb;                               // Xb dead during attn
    __hip_bfloat16* pO1 = (__hip_bfloat16*)d_out + NX;      // d_out[8,16MB)
    __hip_bfloat16* wvt = kb;                               // kb dead after attn

    conv_x<<<2048, 256, 0, stream>>>(lstm, Xb, (int)(NX / 4));
    conv_w<<<dim3(256, 4), 256, 0, stream>>>(Wq, Wk, Wv, Wo, Wqb);

    dim3 gg(MROWS / 64, HID / 64), bb(256);
    gemm_qkv_fused<<<gg, bb, 0, stream>>>(Xb, Wqb, Wkb, Wvb, bq, bk, bv, qb, kb, vT);
    attn<<<dim3(NG * (SEQ / 128) * 2), bb, 0, stream>>>(qb, kb, vT, mask, pO0, pO1, lpp);
    attn_reduce<<<dim3(2048), bb, 0, stream>>>(pO0, pO1, lpp, wvt);
    gemm_out<<<gg, bb, 0, stream>>>(wvt, Wob, bo, out);
}

// Round 14
// 132.016 us; speedup vs baseline: 1.0442x; 1.0442x over previous
//
#include <hip/hip_runtime.h>
#include <hip/hip_bf16.h>

// Problem constants
#define HID 512
#define SEQ 2048
#define NG 32            // (B*NUM_HEADS) after the faithful-to-source flat reshape
#define HD 64
#define MROWS 8192       // B*SEQ
#define LDP 72           // padded LDS row stride (elems) = 144B
// 1/sqrt(512) * log2(e): folded into Q so softmax is exp2(s)
#define QSC 0.0637587178f

typedef __bf16 bf16x8 __attribute__((ext_vector_type(8)));
typedef float f32x4 __attribute__((ext_vector_type(4)));

#define MFMA(a, b, c) __builtin_amdgcn_mfma_f32_16x16x32_bf16((a), (b), (c), 0, 0, 0)

// ---------------------------------------------------------------------------
// prep: f32 -> bf16 vectorized converts
// ---------------------------------------------------------------------------
__global__ __launch_bounds__(256) void conv_x(const float* __restrict__ src,
                                              __hip_bfloat16* __restrict__ dst, int n4) {
    int stride = gridDim.x * 256;
    for (int i = blockIdx.x * 256 + threadIdx.x; i < n4; i += stride) {
        float4 v = *(const float4*)(src + (size_t)i * 4);
        union { __hip_bfloat16 h[4]; uint2 u; } p;
        p.h[0] = __float2bfloat16(v.x); p.h[1] = __float2bfloat16(v.y);
        p.h[2] = __float2bfloat16(v.z); p.h[3] = __float2bfloat16(v.w);
        *(uint2*)(dst + (size_t)i * 4) = p.u;
    }
}

__global__ __launch_bounds__(256) void conv_w(const float* __restrict__ a,
                                              const float* __restrict__ b,
                                              const float* __restrict__ c,
                                              const float* __restrict__ d,
                                              __hip_bfloat16* __restrict__ out) {
    int which = blockIdx.y;
    const float* s = which == 0 ? a : (which == 1 ? b : (which == 2 ? c : d));
    __hip_bfloat16* o = out + (size_t)which * (HID * HID);
    int i = blockIdx.x * 256 + threadIdx.x;   // 65536 float4 per W
    float4 v = *(const float4*)(s + (size_t)i * 4);
    union { __hip_bfloat16 h[4]; uint2 u; } p;
    p.h[0] = __float2bfloat16(v.x); p.h[1] = __float2bfloat16(v.y);
    p.h[2] = __float2bfloat16(v.z); p.h[3] = __float2bfloat16(v.w);
    *(uint2*)(o + (size_t)i * 4) = p.u;
}

// ---------------------------------------------------------------------------
// Fused QKV GEMM with T14 register prefetch across the stage barrier.
// q pre-scaled by QSC; v written transposed per head: vT[g][d][i].
// ---------------------------------------------------------------------------
__global__ __launch_bounds__(256) void gemm_qkv_fused(
        const __hip_bfloat16* __restrict__ Xb,
        const __hip_bfloat16* __restrict__ Wqb, const __hip_bfloat16* __restrict__ Wkb,
        const __hip_bfloat16* __restrict__ Wvb,
        const float* __restrict__ bq, const float* __restrict__ bk, const float* __restrict__ bv,
        __hip_bfloat16* __restrict__ qout, __hip_bfloat16* __restrict__ kout,
        __hip_bfloat16* __restrict__ vT) {
    __shared__ __hip_bfloat16 Xs[64][LDP];
    __shared__ __hip_bfloat16 Wqs[64][LDP];
    __shared__ __hip_bfloat16 Wks[64][LDP];
    __shared__ __hip_bfloat16 Wvs[64][LDP];
    const int tid = threadIdx.x;
    const int w = tid >> 6, l = tid & 63;
    const int row0 = blockIdx.x * 64, col0 = blockIdx.y * 64;

    const int r0 = tid >> 3, r1 = (tid + 256) >> 3;
    const int cc0 = (tid & 7) * 8;
    uint4 px0, px1, pq0, pq1, pk0, pk1, pv0, pv1;
    {
        px0 = *(const uint4*)(Xb  + (size_t)(row0 + r0) * HID + cc0);
        px1 = *(const uint4*)(Xb  + (size_t)(row0 + r1) * HID + cc0);
        pq0 = *(const uint4*)(Wqb + (size_t)(col0 + r0) * HID + cc0);
        pq1 = *(const uint4*)(Wqb + (size_t)(col0 + r1) * HID + cc0);
        pk0 = *(const uint4*)(Wkb + (size_t)(col0 + r0) * HID + cc0);
        pk1 = *(const uint4*)(Wkb + (size_t)(col0 + r1) * HID + cc0);
        pv0 = *(const uint4*)(Wvb + (size_t)(col0 + r0) * HID + cc0);
        pv1 = *(const uint4*)(Wvb + (size_t)(col0 + r1) * HID + cc0);
    }

    f32x4 aq[4] = {}, ak[4] = {}, av[4] = {};
    for (int kt = 0; kt < 8; ++kt) {
        __syncthreads();
        *(uint4*)&Xs[r0][cc0]  = px0;  *(uint4*)&Xs[r1][cc0]  = px1;
        *(uint4*)&Wqs[r0][cc0] = pq0;  *(uint4*)&Wqs[r1][cc0] = pq1;
        *(uint4*)&Wks[r0][cc0] = pk0;  *(uint4*)&Wks[r1][cc0] = pk1;
        *(uint4*)&Wvs[r0][cc0] = pv0;  *(uint4*)&Wvs[r1][cc0] = pv1;
        __syncthreads();
        if (kt < 7) {
            size_t go = (size_t)(kt + 1) * 64 + cc0;
            px0 = *(const uint4*)(Xb  + (size_t)(row0 + r0) * HID + go);
            px1 = *(const uint4*)(Xb  + (size_t)(row0 + r1) * HID + go);
            pq0 = *(const uint4*)(Wqb + (size_t)(col0 + r0) * HID + go);
            pq1 = *(const uint4*)(Wqb + (size_t)(col0 + r1) * HID + go);
            pk0 = *(const uint4*)(Wkb + (size_t)(col0 + r0) * HID + go);
            pk1 = *(const uint4*)(Wkb + (size_t)(col0 + r1) * HID + go);
            pv0 = *(const uint4*)(Wvb + (size_t)(col0 + r0) * HID + go);
            pv1 = *(const uint4*)(Wvb + (size_t)(col0 + r1) * HID + go);
        }
        for (int dk = 0; dk < 2; ++dk) {
            bf16x8 a = *(const bf16x8*)&Xs[w * 16 + (l & 15)][dk * 32 + 8 * (l >> 4)];
            for (int nt = 0; nt < 4; ++nt) {
                int rr = nt * 16 + (l & 15), cc = dk * 32 + 8 * (l >> 4);
                aq[nt] = MFMA(a, *(const bf16x8*)&Wqs[rr][cc], aq[nt]);
                ak[nt] = MFMA(a, *(const bf16x8*)&Wks[rr][cc], ak[nt]);
                av[nt] = MFMA(a, *(const bf16x8*)&Wvs[rr][cc], av[nt]);
            }
        }
    }
    // epilogue
    const int g = row0 >> 8;
    const int rbase = (row0 & 255) + w * 16 + 4 * (l >> 4);
    for (int nt = 0; nt < 4; ++nt) {
        int n = col0 + nt * 16 + (l & 15);
        float bqv = bq[n], bkv = bk[n], bvv = bv[n];
        int d = n & 63;   // col0 is a multiple of 64
        for (int jj = 0; jj < 4; ++jj) {
            int r = row0 + w * 16 + 4 * (l >> 4) + jj;
            qout[(size_t)r * HID + n] = __float2bfloat16((aq[nt][jj] + bqv) * QSC);
            kout[(size_t)r * HID + n] = __float2bfloat16(ak[nt][jj] + bkv);
            vT[(size_t)g * (HD * SEQ) + (size_t)d * SEQ + (rbase + jj) * 8 + blockIdx.y] =
                __float2bfloat16(av[nt][jj] + bvv);
        }
    }
}

// ---------------------------------------------------------------------------
// GEMM: out_f32[M x 512] = X_bf16 @ Wo_bf16^T + bo, with T14 reg prefetch.
// ---------------------------------------------------------------------------
__global__ __launch_bounds__(256) void gemm_out(const __hip_bfloat16* __restrict__ X,
                                                const __hip_bfloat16* __restrict__ W,
                                                const float* __restrict__ bias,
                                                float* __restrict__ out) {
    __shared__ __hip_bfloat16 Xs[64][LDP];
    __shared__ __hip_bfloat16 Ws[64][LDP];
    const int tid = threadIdx.x;
    const int w = tid >> 6, l = tid & 63;
    const int row0 = blockIdx.x * 64, col0 = blockIdx.y * 64;

    const int r0 = tid >> 3, r1 = (tid + 256) >> 3;
    const int cc0 = (tid & 7) * 8;
    uint4 px0 = *(const uint4*)(X + (size_t)(row0 + r0) * HID + cc0);
    uint4 px1 = *(const uint4*)(X + (size_t)(row0 + r1) * HID + cc0);
    uint4 pw0 = *(const uint4*)(W + (size_t)(col0 + r0) * HID + cc0);
    uint4 pw1 = *(const uint4*)(W + (size_t)(col0 + r1) * HID + cc0);

    f32x4 acc[4] = {};
    for (int kt = 0; kt < 8; ++kt) {
        __syncthreads();
        *(uint4*)&Xs[r0][cc0] = px0;  *(uint4*)&Xs[r1][cc0] = px1;
        *(uint4*)&Ws[r0][cc0] = pw0;  *(uint4*)&Ws[r1][cc0] = pw1;
        __syncthreads();
        if (kt < 7) {
            size_t go = (size_t)(kt + 1) * 64 + cc0;
            px0 = *(const uint4*)(X + (size_t)(row0 + r0) * HID + go);
            px1 = *(const uint4*)(X + (size_t)(row0 + r1) * HID + go);
            pw0 = *(const uint4*)(W + (size_t)(col0 + r0) * HID + go);
            pw1 = *(const uint4*)(W + (size_t)(col0 + r1) * HID + go);
        }
        for (int dk = 0; dk < 2; ++dk) {
            bf16x8 a = *(const bf16x8*)&Xs[w * 16 + (l & 15)][dk * 32 + 8 * (l >> 4)];
            for (int nt = 0; nt < 4; ++nt) {
                bf16x8 b = *(const bf16x8*)&Ws[nt * 16 + (l & 15)][dk * 32 + 8 * (l >> 4)];
                acc[nt] = MFMA(a, b, acc[nt]);
            }
        }
    }
    for (int nt = 0; nt < 4; ++nt) {
        int n = col0 + nt * 16 + (l & 15);
        float bv = bias[n];
        for (int jj = 0; jj < 4; ++jj) {
            int r = row0 + w * 16 + 4 * (l >> 4) + jj;
            out[(size_t)r * HID + n] = acc[nt][jj] + bv;
        }
    }
}

// ---------------------------------------------------------------------------
// Attention, swapped-QK^T in-register softmax (round-12 structure) with a
// 2-TILE UNROLL: tiles t (buf0) and t+1 (buf1) are computed back-to-back as
// independent instruction streams between barriers (the kernel is latency-
// bound: ~4900 cyc/iter vs ~500 cyc of pipe work at 2 waves/SIMD — round-13
// diagnosis). Restage writes both buffers, then both next loads issue.
// ---------------------------------------------------------------------------
#define ATTN_TILE(bf)                                                              \
    {                                                                              \
        f32x4 sacc[2][4];                                                          \
        for (int nt = 0; nt < 4; ++nt) {                                           \
            f32x4 binit = *(const f32x4*)&sb[bf][nt * 16 + 4 * h];                 \
            sacc[0][nt] = binit;                                                   \
            sacc[1][nt] = binit;                                                   \
        }                                                                          \
        for (int dk = 0; dk < 2; ++dk)                                             \
            for (int nt = 0; nt < 4; ++nt) {                                       \
                bf16x8 kf = *(const bf16x8*)&Ks[bf][nt * 16 + q][dk * 32 + 8 * h]; \
                sacc[0][nt] = MFMA(kf, qf[0][dk], sacc[0][nt]);                    \
                sacc[1][nt] = MFMA(kf, qf[1][dk], sacc[1][nt]);                    \
            }                                                                      \
        union pk_t { bf16x8 v; __hip_bfloat16 hh[8]; } pa[2][2];                   \
        for (int m = 0; m < 2; ++m)                                                \
            for (int kk = 0; kk < 2; ++kk)                                         \
                for (int j = 0; j < 4; ++j) {                                      \
                    pa[m][kk].hh[j]     = __float2bfloat16(exp2f(sacc[m][kk][j]));     \
                    pa[m][kk].hh[j + 4] = __float2bfloat16(exp2f(sacc[m][kk + 2][j])); \
                }                                                                  \
        for (int kk = 0; kk < 2; ++kk) {                                           \
            lsum[0] = MFMA(pa[0][kk].v, ones, lsum[0]);                            \
            lsum[1] = MFMA(pa[1][kk].v, ones, lsum[1]);                            \
            for (int dt = 0; dt < 4; ++dt) {                                       \
                bf16x8 bv = *(const bf16x8*)&VTs[bf][dt * 16 + q][kk * 32 + 8 * h];\
                acc[0][dt] = MFMA(pa[0][kk].v, bv, acc[0][dt]);                    \
                acc[1][dt] = MFMA(pa[1][kk].v, bv, acc[1][dt]);                    \
            }                                                                      \
        }                                                                          \
    }

__global__ __launch_bounds__(256) void attn(const __hip_bfloat16* __restrict__ qg,
                                            const __hip_bfloat16* __restrict__ kg,
                                            const __hip_bfloat16* __restrict__ vT,
                                            const int* __restrict__ mask,
                                            __hip_bfloat16* __restrict__ wvt) {
    __shared__ __hip_bfloat16 Ks[2][64][LDP];
    __shared__ __hip_bfloat16 VTs[2][64][LDP];
    __shared__ float sb[2][64];

    const int tid = threadIdx.x;
    const int w = tid >> 6, l = tid & 63;
    const int h = l >> 4, q = l & 15;
    // XCD-chunked swizzle: 512 blocks % 8 == 0 -> bijective
    const int bid = (blockIdx.x & 7) * 64 + (blockIdx.x >> 3);
    const int g = bid >> 4, qt = bid & 15;
    const size_t hb = (size_t)g * (SEQ * HD);

    // Q fragments in registers (one-time global read, L2-resident)
    bf16x8 qf[2][2];
    for (int m = 0; m < 2; ++m)
        for (int dk = 0; dk < 2; ++dk)
            qf[m][dk] = *(const bf16x8*)(qg + hb +
                (size_t)(qt * 128 + w * 32 + m * 16 + q) * HD + dk * 32 + 8 * h);

    const int r0 = tid >> 3, r1 = (tid + 256) >> 3;
    const int cc0 = (tid & 7) * 8;
    // permuted V dest base: keys cc0..cc0+3 -> cA..cA+3, cc0+4..+7 -> cA+8..+11
    const int ntc = cc0 >> 4;
    const int cA = (ntc & 1) * 32 + ((cc0 >> 2) & 3) * 8 + (ntc >> 1) * 4;

    const __bf16 kOne = (__bf16)1.0f;
    const bf16x8 ones = {kOne, kOne, kOne, kOne, kOne, kOne, kOne, kOne};

    f32x4 acc[2][4] = {};
    f32x4 lsum[2] = {};

    // ---- prologue: tiles 0,1 -> buf0,buf1; prefetch tiles 2,3 into regs ----
    uint4 ka0, ka1, va0, va1; int ma;   // set A (even tiles)
    uint4 kb0, kb1, vb0, vb1; int mb;   // set B (odd tiles)

    ka0 = *(const uint4*)(kg + hb + (size_t)r0 * HD + cc0);
    ka1 = *(const uint4*)(kg + hb + (size_t)r1 * HD + cc0);
    va0 = *(const uint4*)(vT + hb + (size_t)r0 * SEQ + cc0);
    va1 = *(const uint4*)(vT + hb + (size_t)r1 * SEQ + cc0);
    ma  = (tid < 64) ? mask[tid] : 0;
    kb0 = *(const uint4*)(kg + hb + (size_t)(64 + r0) * HD + cc0);
    kb1 = *(const uint4*)(kg + hb + (size_t)(64 + r1) * HD + cc0);
    vb0 = *(const uint4*)(vT + hb + (size_t)r0 * SEQ + 64 + cc0);
    vb1 = *(const uint4*)(vT + hb + (size_t)r1 * SEQ + 64 + cc0);
    mb  = (tid < 64) ? mask[64 + tid] : 0;

    *(uint4*)&Ks[0][r0][cc0] = ka0;
    *(uint4*)&Ks[0][r1][cc0] = ka1;
    *(uint2*)&VTs[0][r0][cA]     = make_uint2(va0.x, va0.y);
    *(uint2*)&VTs[0][r0][cA + 8] = make_uint2(va0.z, va0.w);
    *(uint2*)&VTs[0][r1][cA]     = make_uint2(va1.x, va1.y);
    *(uint2*)&VTs[0][r1][cA + 8] = make_uint2(va1.z, va1.w);
    if (tid < 64) sb[0][tid] = ma ? 0.f : -1e38f;
    *(uint4*)&Ks[1][r0][cc0] = kb0;
    *(uint4*)&Ks[1][r1][cc0] = kb1;
    *(uint2*)&VTs[1][r0][cA]     = make_uint2(vb0.x, vb0.y);
    *(uint2*)&VTs[1][r0][cA + 8] = make_uint2(vb0.z, vb0.w);
    *(uint2*)&VTs[1][r1][cA]     = make_uint2(vb1.x, vb1.y);
    *(uint2*)&VTs[1][r1][cA + 8] = make_uint2(vb1.z, vb1.w);
    if (tid < 64) sb[1][tid] = mb ? 0.f : -1e38f;

    {   // prefetch tiles 2,3
        const size_t ko2 = hb + (size_t)2 * 64 * HD, ko3 = hb + (size_t)3 * 64 * HD;
        ka0 = *(const uint4*)(kg + ko2 + (size_t)r0 * HD + cc0);
        ka1 = *(const uint4*)(kg + ko2 + (size_t)r1 * HD + cc0);
        va0 = *(const uint4*)(vT + hb + (size_t)r0 * SEQ + 128 + cc0);
        va1 = *(const uint4*)(vT + hb + (size_t)r1 * SEQ + 128 + cc0);
        kb0 = *(const uint4*)(kg + ko3 + (size_t)r0 * HD + cc0);
        kb1 = *(const uint4*)(kg + ko3 + (size_t)r1 * HD + cc0);
        vb0 = *(const uint4*)(vT + hb + (size_t)r0 * SEQ + 192 + cc0);
        vb1 = *(const uint4*)(vT + hb + (size_t)r1 * SEQ + 192 + cc0);
        if (tid < 64) { ma = mask[128 + tid]; mb = mask[192 + tid]; }
    }
    __syncthreads();

    for (int kt = 0; kt < 32; kt += 2) {
        // two independent tile streams between barriers (ILP x2)
        ATTN_TILE(0)
        ATTN_TILE(1)
        __syncthreads();   // all reads of both buffers done
        if (kt + 2 < 32) {
            *(uint4*)&Ks[0][r0][cc0] = ka0;
            *(uint4*)&Ks[0][r1][cc0] = ka1;
            *(uint2*)&VTs[0][r0][cA]     = make_uint2(va0.x, va0.y);
            *(uint2*)&VTs[0][r0][cA + 8] = make_uint2(va0.z, va0.w);
            *(uint2*)&VTs[0][r1][cA]     = make_uint2(va1.x, va1.y);
            *(uint2*)&VTs[0][r1][cA + 8] = make_uint2(va1.z, va1.w);
            if (tid < 64) sb[0][tid] = ma ? 0.f : -1e38f;
            *(uint4*)&Ks[1][r0][cc0] = kb0;
            *(uint4*)&Ks[1][r1][cc0] = kb1;
            *(uint2*)&VTs[1][r0][cA]     = make_uint2(vb0.x, vb0.y);
            *(uint2*)&VTs[1][r0][cA + 8] = make_uint2(vb0.z, vb0.w);
            *(uint2*)&VTs[1][r1][cA]     = make_uint2(vb1.x, vb1.y);
            *(uint2*)&VTs[1][r1][cA + 8] = make_uint2(vb1.z, vb1.w);
            if (tid < 64) sb[1][tid] = mb ? 0.f : -1e38f;
            if (kt + 4 < 32) {
                const size_t koA = hb + (size_t)(kt + 4) * 64 * HD;
                const size_t koB = hb + (size_t)(kt + 5) * 64 * HD;
                ka0 = *(const uint4*)(kg + koA + (size_t)r0 * HD + cc0);
                ka1 = *(const uint4*)(kg + koA + (size_t)r1 * HD + cc0);
                va0 = *(const uint4*)(vT + hb + (size_t)r0 * SEQ + (kt + 4) * 64 + cc0);
                va1 = *(const uint4*)(vT + hb + (size_t)r1 * SEQ + (kt + 4) * 64 + cc0);
                kb0 = *(const uint4*)(kg + koB + (size_t)r0 * HD + cc0);
                kb1 = *(const uint4*)(kg + koB + (size_t)r1 * HD + cc0);
                vb0 = *(const uint4*)(vT + hb + (size_t)r0 * SEQ + (kt + 5) * 64 + cc0);
                vb1 = *(const uint4*)(vT + hb + (size_t)r1 * SEQ + (kt + 5) * 64 + cc0);
                if (tid < 64) { ma = mask[(kt + 4) * 64 + tid]; mb = mask[(kt + 5) * 64 + tid]; }
            }
            __syncthreads();   // restaged buffers visible
        }
    }

    // lane's lsum[m][jj] IS the row-sum for acc row jj of subtile m
    for (int m = 0; m < 2; ++m) {
        float rinv[4];
        for (int jj = 0; jj < 4; ++jj) rinv[jj] = 1.f / lsum[m][jj];
        const int ibase = qt * 128 + w * 32 + m * 16 + 4 * h;
        for (int dt = 0; dt < 4; ++dt) {
            int d = dt * 16 + q;
            union { __hip_bfloat16 hh[4]; uint2 u; } o;
            for (int jj = 0; jj < 4; ++jj)
                o.hh[jj] = __float2bfloat16(acc[m][dt][jj] * rinv[jj]);
            *(uint2*)(wvt + (size_t)g * (HD * SEQ) + (size_t)d * SEQ + ibase) = o.u;
        }
    }
}

// ---------------------------------------------------------------------------
// ws layout (26 MB peak): Xb [0,8MB) -> aliased by wvt after QKV GEMM;
// W bf16 [8,10MB); qb [10,18MB); kb [18,26MB).
// vT lives in d_out's first 8 MB (dead before gemm_out overwrites d_out).
// ---------------------------------------------------------------------------
extern "C" void kernel_launch(void* const* d_in, const int* in_sizes, int n_in,
                              void* d_out, int out_size, void* d_ws, size_t ws_size,
                              hipStream_t stream) {
    const float* lstm = (const float*)d_in[0];
    const int* mask = (const int*)d_in[1];
    const float* Wq = (const float*)d_in[2]; const float* bq = (const float*)d_in[3];
    const float* Wk = (const float*)d_in[4]; const float* bk = (const float*)d_in[5];
    const float* Wv = (const float*)d_in[6]; const float* bv = (const float*)d_in[7];
    const float* Wo = (const float*)d_in[8]; const float* bo = (const float*)d_in[9];
    float* out = (float*)d_out;

    const size_t NX = (size_t)MROWS * HID;    // 4M elems
    const size_t NW = (size_t)HID * HID;      // 256K elems
    __hip_bfloat16* Xb  = (__hip_bfloat16*)d_ws;            // 4M elems (8MB)
    __hip_bfloat16* Wqb = Xb + NX;                          // 256K
    __hip_bfloat16* Wkb = Wqb + NW;
    __hip_bfloat16* Wvb = Wkb + NW;
    __hip_bfloat16* Wob = Wvb + NW;
    __hip_bfloat16* qb  = Wob + NW;                         // 4M
    __hip_bfloat16* kb  = qb + NX;                          // 4M
    __hip_bfloat16* vT  = (__hip_bfloat16*)d_out;           // scratch in d_out[0,8MB)
    __hip_bfloat16* wvt = Xb;                               // alias: Xb dead after QKV GEMM

    conv_x<<<2048, 256, 0, stream>>>(lstm, Xb, (int)(NX / 4));
    conv_w<<<dim3(256, 4), 256, 0, stream>>>(Wq, Wk, Wv, Wo, Wqb);

    dim3 gg(MROWS / 64, HID / 64), bb(256);
    gemm_qkv_fused<<<gg, bb, 0, stream>>>(Xb, Wqb, Wkb, Wvb, bq, bk, bv, qb, kb, vT);
    attn<<<dim3(NG * (SEQ / 128)), bb, 0, stream>>>(qb, kb, vT, mask, wvt);
    gemm_out<<<gg, bb, 0, stream>>>(wvt, Wob, bo, out);
}